// Round 5
// baseline (247.523 us; speedup 1.0000x reference)
//
#include <hip/hip_runtime.h>
#include <hip/hip_bf16.h>

// Problem constants
#define B_TOT  4096
#define M_TOT  65536
#define D_V    64
#define KD     96            // 64 (keys) + 32 (0.5*contexts); Q side pre-scaled by log2e
#define BQ     256           // q rows per block (4 waves x 64)
#define BN     64            // keys per inner tile
#define NQT    (B_TOT / BQ)  // 16
#define SP     72            // padded LDS row stride (bf16 elems), 144B, 16B-aligned rows
#define SHIFT2 23.0f         // fixed softmax shift in exp2 domain

using short8   = __attribute__((ext_vector_type(8))) short;
using floatx4  = __attribute__((ext_vector_type(4))) float;
using ushort4v = __attribute__((ext_vector_type(4))) unsigned short;

static __device__ __forceinline__ unsigned short f2bf(float f) {
  return __builtin_bit_cast(unsigned short, __float2bfloat16(f));
}

static __device__ __forceinline__ floatx4 mfma16(short8 a, short8 b, floatx4 c) {
  return __builtin_amdgcn_mfma_f32_16x16x32_bf16(a, b, c, 0, 0, 0);
}

#define LOG2E 1.4426950408889634f

// ---- fused prep kernel ------------------------------------------------------
// blocks [0,1024): kc2   [1024,2048): vt2   [2048,3584): qc   [3584,3840): bias

#define NB_K 1024
#define NB_V 1024
#define NB_Q 1536
#define NB_B 256

__global__ __launch_bounds__(256) void
prep_all(const float* __restrict__ q, const float* __restrict__ ctx,
         const float* __restrict__ keys, const float* __restrict__ ctxs,
         const float* __restrict__ vals, const float* __restrict__ ts,
         const int* __restrict__ used,
         unsigned short* __restrict__ qc, unsigned short* __restrict__ kc2,
         unsigned short* __restrict__ vt2, float* __restrict__ bias)
{
  __shared__ float sbuf[64 * 65 + 64 * 33];
  const int bid = blockIdx.x;
  const int t = threadIdx.x;

  if (bid < NB_K) {
    // K+context in MFMA fragment-linear order:
    // kc2[g][c][lane][8], c = nt*3+s; elem = Kc[m=g*64+nt*16+(lane&15)][kk=s*32+(lane>>4)*8+j]
    float* lk = sbuf;               // [64][65]
    float* lx = sbuf + 64 * 65;     // [64][33]
    const int g = bid;
    const float* kb = keys + (size_t)g * 64 * 64;
    const float* xb = ctxs + (size_t)g * 64 * 32;
#pragma unroll
    for (int i = 0; i < 16; ++i) {
      int idx = i * 256 + t;
      lk[(idx >> 6) * 65 + (idx & 63)] = kb[idx];
    }
#pragma unroll
    for (int i = 0; i < 8; ++i) {
      int idx = i * 256 + t;
      lx[(idx >> 5) * 33 + (idx & 31)] = xb[idx];
    }
    __syncthreads();
    unsigned short* outp = kc2 + (size_t)g * 6144;
#pragma unroll
    for (int p = 0; p < 3; ++p) {
      int o = p * 2048 + t * 8;
      int c = o >> 9;
      int lane = (o >> 3) & 63;
      int lqq = lane >> 4, lcc = lane & 15;
      int nt = c / 3, s = c - nt * 3;
      int ml = nt * 16 + lcc;
      short8 v;
#pragma unroll
      for (int j = 0; j < 8; ++j) {
        int kk = s * 32 + lqq * 8 + j;
        float f = (kk < 64) ? lk[ml * 65 + kk] : lx[ml * 33 + (kk - 64)];
        v[j] = (short)f2bf(f);
      }
      *reinterpret_cast<short8*>(outp + o) = v;
    }
  } else if (bid < NB_K + NB_V) {
    // V fragment-linear: vt2[g][c2][lane][8], c2=h*4+nd;
    // elem = V[m=g*64+h*32+(lane>>4)*8+j][d=nd*16+(lane&15)]
    float* lv = sbuf;               // [64][65]
    const int g = bid - NB_K;
    const float* vb = vals + (size_t)g * 64 * 64;
#pragma unroll
    for (int i = 0; i < 16; ++i) {
      int idx = i * 256 + t;
      lv[(idx >> 6) * 65 + (idx & 63)] = vb[idx];
    }
    __syncthreads();
    unsigned short* outp = vt2 + (size_t)g * 4096;
#pragma unroll
    for (int p = 0; p < 2; ++p) {
      int o = p * 2048 + t * 8;
      int c2 = o >> 9;
      int lane = (o >> 3) & 63;
      int lqq = lane >> 4, lcc = lane & 15;
      int h = c2 >> 2, nd = c2 & 3;
      short8 w;
#pragma unroll
      for (int j = 0; j < 8; ++j)
        w[j] = (short)f2bf(lv[(h * 32 + lqq * 8 + j) * 65 + nd * 16 + lcc]);
      *reinterpret_cast<short8*>(outp + o) = w;
    }
  } else if (bid < NB_K + NB_V + NB_Q) {
    int tt = (bid - NB_K - NB_V) * 256 + t;     // 4096*96
    int b = tt / KD, j = tt % KD;
    float v = (j < 64) ? q[b * 64 + j] : 0.5f * ctx[b * 32 + (j - 64)];
    qc[tt] = f2bf(v * LOG2E);
  } else {
    int m = (bid - NB_K - NB_V - NB_Q) * 256 + t;
    bias[m] = used[m] ? (LOG2E * 0.3f * __expf(-0.1f * (1.0f - ts[m])) - SHIFT2) : -1e9f;
  }
}

// ---- flash attention main kernel -------------------------------------------
// grid (NQT, NC); block 256 = 4 waves; each wave owns 64 q rows (4 A-frags).
// S^T = K*Q^T (so P hits LDS as packed b64); P = exp2(S + bias'); linear combine.

template<int NC>
__global__ __launch_bounds__(256, 2) void
flash_kernel(const unsigned short* __restrict__ qc,
             const unsigned short* __restrict__ kc2,
             const unsigned short* __restrict__ vt2,
             const float* __restrict__ bias,
             float* __restrict__ opart, float* __restrict__ lpart)
{
  constexpr int MC = M_TOT / NC;       // keys per block
  constexpr int NIT = MC / BN;
  __shared__ __align__(16) unsigned short pt[4][2][16][SP];  // [wave][slot][qrow][key]
  const int qt    = blockIdx.x;
  const int chunk = blockIdx.y;
  const int tid   = threadIdx.x;
  const int w     = tid >> 6;
  const int lane  = tid & 63;
  const int lq    = lane >> 4;
  const int lc    = lane & 15;

  floatx4 zero; zero[0] = 0.f; zero[1] = 0.f; zero[2] = 0.f; zero[3] = 0.f;

  // Q fragments (B-operand): rows qt*256 + w*64 + a*16 + lc
  short8 qf[4][3];
#pragma unroll
  for (int a = 0; a < 4; ++a) {
    const unsigned short* qrp = qc + (size_t)(qt * BQ + w * 64 + a * 16 + lc) * KD + lq * 8;
    qf[a][0] = *reinterpret_cast<const short8*>(qrp);
    qf[a][1] = *reinterpret_cast<const short8*>(qrp + 32);
    qf[a][2] = *reinterpret_cast<const short8*>(qrp + 64);
  }

  const int g0 = chunk * (MC / 64);
  const unsigned short* kptr = kc2 + (size_t)g0 * 6144 + lane * 8;
  const unsigned short* vptr = vt2 + (size_t)g0 * 4096 + lane * 8;
  const float* bptr = bias + chunk * MC + lq * 4;   // float4 per (it, nt)

  floatx4 o[4][4];
#pragma unroll
  for (int a = 0; a < 4; ++a)
#pragma unroll
    for (int nd = 0; nd < 4; ++nd) o[a][nd] = zero;
  float lsum[4] = {0.f, 0.f, 0.f, 0.f};

  unsigned short* wbase = &pt[w][0][0][0];

#pragma unroll 1
  for (int it = 0; it < NIT; ++it) {
    // dense coalesced frag loads (each = 1KB per wave), shared across 4 a-tiles
    short8 kf[12];
#pragma unroll
    for (int c = 0; c < 12; ++c)
      kf[c] = *reinterpret_cast<const short8*>(kptr + c * 512);
    short8 vf[8];
#pragma unroll
    for (int c = 0; c < 8; ++c)
      vf[c] = *reinterpret_cast<const short8*>(vptr + c * 512);

#pragma unroll
    for (int a = 0; a < 4; ++a) {
      unsigned short* slot = wbase + (a & 1) * (16 * SP);
      // S^T tiles: rows = keys (nt*16 + lq*4 + r), col = qrow = lc
#pragma unroll
      for (int nt = 0; nt < 4; ++nt) {
        floatx4 acc = zero;
        acc = mfma16(kf[nt * 3 + 0], qf[a][0], acc);
        acc = mfma16(kf[nt * 3 + 1], qf[a][1], acc);
        acc = mfma16(kf[nt * 3 + 2], qf[a][2], acc);
        floatx4 b4 = *reinterpret_cast<const floatx4*>(bptr + nt * 16);
        float p0 = __builtin_amdgcn_exp2f(acc[0] + b4[0]);
        float p1 = __builtin_amdgcn_exp2f(acc[1] + b4[1]);
        float p2 = __builtin_amdgcn_exp2f(acc[2] + b4[2]);
        float p3 = __builtin_amdgcn_exp2f(acc[3] + b4[3]);
        lsum[a] += (p0 + p1) + (p2 + p3);
        ushort4v pk;
        pk[0] = f2bf(p0); pk[1] = f2bf(p1); pk[2] = f2bf(p2); pk[3] = f2bf(p3);
        *reinterpret_cast<ushort4v*>(slot + lc * SP + nt * 16 + lq * 4) = pk;
      }
      // P as A-frags (qrow = lc, 8 consecutive keys) — same-wave DS ordering
      short8 pa0 = *reinterpret_cast<const short8*>(slot + lc * SP + lq * 8);
      short8 pa1 = *reinterpret_cast<const short8*>(slot + lc * SP + 32 + lq * 8);
#pragma unroll
      for (int nd = 0; nd < 4; ++nd) {
        o[a][nd] = mfma16(pa0, vf[nd],     o[a][nd]);
        o[a][nd] = mfma16(pa1, vf[4 + nd], o[a][nd]);
      }
    }
    kptr += 12 * 512;
    vptr += 8 * 512;
    bptr += BN;
  }

  // epilogue: write partial O and l
  const int pb = qt * NC + chunk;
  float* op = opart + (size_t)pb * BQ * D_V;
#pragma unroll
  for (int a = 0; a < 4; ++a) {
    const int rbase = w * 64 + a * 16 + lq * 4;
#pragma unroll
    for (int nd = 0; nd < 4; ++nd)
#pragma unroll
      for (int r = 0; r < 4; ++r)
        op[(rbase + r) * D_V + nd * 16 + lc] = o[a][nd][r];
    // reduce lsum over the 4 lq-groups (lanes differing in bits 4,5)
    float ls = lsum[a];
    ls += __shfl_xor(ls, 16, 64);
    ls += __shfl_xor(ls, 32, 64);
    if (lq == 0) lpart[(size_t)pb * BQ + w * 64 + a * 16 + lc] = ls;
  }
}

// ---- final reduction --------------------------------------------------------

template<int NC>
__global__ void reduce_out(const float* __restrict__ opart, const float* __restrict__ lpart,
                           float* __restrict__ out) {
  int t = blockIdx.x * 256 + threadIdx.x;   // 262144 total
  int b = t >> 6, d = t & 63;
  int qt = b >> 8, r = b & 255;
  float os = 0.f, ls = 0.f;
#pragma unroll
  for (int c = 0; c < NC; ++c) {
    os += opart[((size_t)(qt * NC + c) * BQ + r) * D_V + d];
    ls += lpart[(size_t)(qt * NC + c) * BQ + r];
  }
  out[t] = os / ls;
}

// ---- launcher ---------------------------------------------------------------

template<int NC>
static void launch_all(const float* query, const float* context, const float* keys,
                       const float* values, const float* contexts, const float* ts,
                       const int* used, float* out, char* ws, hipStream_t stream) {
  unsigned short* qc  = (unsigned short*)ws;  ws += (size_t)B_TOT * KD * 2;
  unsigned short* kc2 = (unsigned short*)ws;  ws += (size_t)M_TOT * KD * 2;
  unsigned short* vt2 = (unsigned short*)ws;  ws += (size_t)D_V * M_TOT * 2;
  float* bias  = (float*)ws;                  ws += (size_t)M_TOT * 4;
  float* opart = (float*)ws;                  ws += (size_t)NC * B_TOT * D_V * 4;
  float* lpart = (float*)ws;

  prep_all<<<NB_K + NB_V + NB_Q + NB_B, 256, 0, stream>>>(
      query, context, keys, contexts, values, ts, used, qc, kc2, vt2, bias);

  dim3 grid(NQT, NC);
  flash_kernel<NC><<<grid, 256, 0, stream>>>(qc, kc2, vt2, bias, opart, lpart);

  reduce_out<NC><<<(B_TOT * D_V) / 256, 256, 0, stream>>>(opart, lpart, out);
}

extern "C" void kernel_launch(void* const* d_in, const int* in_sizes, int n_in,
                              void* d_out, int out_size, void* d_ws, size_t ws_size,
                              hipStream_t stream) {
  const float* query    = (const float*)d_in[0];
  const float* context  = (const float*)d_in[1];
  const float* keys     = (const float*)d_in[2];
  const float* values   = (const float*)d_in[3];
  const float* contexts = (const float*)d_in[4];
  const float* ts       = (const float*)d_in[5];
  const int*   used     = (const int*)d_in[6];
  float* out = (float*)d_out;
  char* ws = (char*)d_ws;

  const size_t fixed = (size_t)B_TOT * KD * 2 + (size_t)M_TOT * KD * 2 +
                       (size_t)D_V * M_TOT * 2 + (size_t)M_TOT * 4;
  const size_t need32 = fixed + 32ull * ((size_t)B_TOT * D_V * 4 + (size_t)B_TOT * 4);

  if (ws_size >= need32)
    launch_all<32>(query, context, keys, values, contexts, ts, used, out, ws, stream);
  else
    launch_all<16>(query, context, keys, values, contexts, ts, used, out, ws, stream);
}

// Round 6
// 226.162 us; speedup vs baseline: 1.0945x; 1.0945x over previous
//
#include <hip/hip_runtime.h>
#include <hip/hip_bf16.h>

// Problem constants
#define B_TOT  4096
#define M_TOT  65536
#define D_V    64
#define KD     96            // 64 (keys) + 32 (0.5*contexts); Q side pre-scaled by log2e
#define BQ     128           // q rows per block (4 waves x 32)
#define BN     64            // keys per inner tile
#define NQT    (B_TOT / BQ)  // 32
#define SP     72            // padded LDS row stride (bf16 elems), 144B, 16B-aligned rows
#define SHIFT2 23.0f         // fixed softmax shift in exp2 domain

using short8   = __attribute__((ext_vector_type(8))) short;
using floatx4  = __attribute__((ext_vector_type(4))) float;

static __device__ __forceinline__ unsigned short f2bf(float f) {
  return __builtin_bit_cast(unsigned short, __float2bfloat16(f));
}

static __device__ __forceinline__ floatx4 mfma16(short8 a, short8 b, floatx4 c) {
  return __builtin_amdgcn_mfma_f32_16x16x32_bf16(a, b, c, 0, 0, 0);
}

#define LOG2E 1.4426950408889634f

// ---- fused prep kernel ------------------------------------------------------
// blocks [0,1024): kc2   [1024,2048): vt2   [2048,3584): qc   [3584,3840): bias

#define NB_K 1024
#define NB_V 1024
#define NB_Q 1536
#define NB_B 256

__global__ __launch_bounds__(256) void
prep_all(const float* __restrict__ q, const float* __restrict__ ctx,
         const float* __restrict__ keys, const float* __restrict__ ctxs,
         const float* __restrict__ vals, const float* __restrict__ ts,
         const int* __restrict__ used,
         unsigned short* __restrict__ qc, unsigned short* __restrict__ kc2,
         unsigned short* __restrict__ vt2, float* __restrict__ bias)
{
  __shared__ float sbuf[64 * 65 + 64 * 33];
  const int bid = blockIdx.x;
  const int t = threadIdx.x;

  if (bid < NB_K) {
    // K+context in MFMA fragment-linear order:
    // kc2[g][c][lane][8], c = nt*3+s; elem = Kc[m=g*64+nt*16+(lane&15)][kk=s*32+(lane>>4)*8+j]
    float* lk = sbuf;               // [64][65]
    float* lx = sbuf + 64 * 65;     // [64][33]
    const int g = bid;
    const float* kb = keys + (size_t)g * 64 * 64;
    const float* xb = ctxs + (size_t)g * 64 * 32;
#pragma unroll
    for (int i = 0; i < 16; ++i) {
      int idx = i * 256 + t;
      lk[(idx >> 6) * 65 + (idx & 63)] = kb[idx];
    }
#pragma unroll
    for (int i = 0; i < 8; ++i) {
      int idx = i * 256 + t;
      lx[(idx >> 5) * 33 + (idx & 31)] = xb[idx];
    }
    __syncthreads();
    unsigned short* outp = kc2 + (size_t)g * 6144;
#pragma unroll
    for (int p = 0; p < 3; ++p) {
      int o = p * 2048 + t * 8;
      int c = o >> 9;
      int lane = (o >> 3) & 63;
      int lqq = lane >> 4, lcc = lane & 15;
      int nt = c / 3, s = c - nt * 3;
      int ml = nt * 16 + lcc;
      short8 v;
#pragma unroll
      for (int j = 0; j < 8; ++j) {
        int kk = s * 32 + lqq * 8 + j;
        float f = (kk < 64) ? lk[ml * 65 + kk] : lx[ml * 33 + (kk - 64)];
        v[j] = (short)f2bf(f);
      }
      *reinterpret_cast<short8*>(outp + o) = v;
    }
  } else if (bid < NB_K + NB_V) {
    // V fragment-linear: vt2[g][c2][lane][8], c2=h*4+nd;
    // elem = V[m=g*64+h*32+(lane>>4)*8+j][d=nd*16+(lane&15)]
    float* lv = sbuf;               // [64][65]
    const int g = bid - NB_K;
    const float* vb = vals + (size_t)g * 64 * 64;
#pragma unroll
    for (int i = 0; i < 16; ++i) {
      int idx = i * 256 + t;
      lv[(idx >> 6) * 65 + (idx & 63)] = vb[idx];
    }
    __syncthreads();
    unsigned short* outp = vt2 + (size_t)g * 4096;
#pragma unroll
    for (int p = 0; p < 2; ++p) {
      int o = p * 2048 + t * 8;
      int c2 = o >> 9;
      int lane = (o >> 3) & 63;
      int lqq = lane >> 4, lcc = lane & 15;
      int h = c2 >> 2, nd = c2 & 3;
      short8 w;
#pragma unroll
      for (int j = 0; j < 8; ++j)
        w[j] = (short)f2bf(lv[(h * 32 + lqq * 8 + j) * 65 + nd * 16 + lcc]);
      *reinterpret_cast<short8*>(outp + o) = w;
    }
  } else if (bid < NB_K + NB_V + NB_Q) {
    int tt = (bid - NB_K - NB_V) * 256 + t;     // 4096*96
    int b = tt / KD, j = tt % KD;
    float v = (j < 64) ? q[b * 64 + j] : 0.5f * ctx[b * 32 + (j - 64)];
    qc[tt] = f2bf(v * LOG2E);
  } else {
    int m = (bid - NB_K - NB_V - NB_Q) * 256 + t;
    bias[m] = used[m] ? (LOG2E * 0.3f * __expf(-0.1f * (1.0f - ts[m])) - SHIFT2) : -1e9f;
  }
}

// ---- flash attention main kernel -------------------------------------------
// grid (NQT, NC); block 256 = 4 waves; each wave owns 32 q rows (2 A-frags).
// K/V frags staged cooperatively into LDS (global_load_lds, double-buffered,
// one barrier per iter). Fixed-shift softmax: P = exp2(S + bias'); linear combine.

template<int NC>
__global__ __launch_bounds__(256, 3) void
flash_kernel(const unsigned short* __restrict__ qc,
             const unsigned short* __restrict__ kc2,
             const unsigned short* __restrict__ vt2,
             const float* __restrict__ bias,
             float* __restrict__ opart, float* __restrict__ lpart)
{
  constexpr int MC  = M_TOT / NC;      // keys per block
  constexpr int NIT = MC / BN;
  // LDS: two 20KB stage buffers (12KB K-frags + 8KB V-frags each) + P tiles
  __shared__ __align__(16) unsigned short lds_kv[2 * 10240];   // 40960 B
  __shared__ __align__(16) unsigned short pt[4][16][SP];       //  9216 B
  const int qt    = blockIdx.x;
  const int chunk = blockIdx.y;
  const int tid   = threadIdx.x;
  const int w     = tid >> 6;
  const int lane  = tid & 63;
  const int lq    = lane >> 4;
  const int lc    = lane & 15;

  floatx4 zero; zero[0] = 0.f; zero[1] = 0.f; zero[2] = 0.f; zero[3] = 0.f;

  // Q fragments: rows qt*128 + w*32 + a*16 + lc
  short8 qf[2][3];
#pragma unroll
  for (int a = 0; a < 2; ++a) {
    const unsigned short* qrp = qc + (size_t)(qt * BQ + w * 32 + a * 16 + lc) * KD + lq * 8;
    qf[a][0] = *reinterpret_cast<const short8*>(qrp);
    qf[a][1] = *reinterpret_cast<const short8*>(qrp + 32);
    qf[a][2] = *reinterpret_cast<const short8*>(qrp + 64);
  }

  short8 ones;
#pragma unroll
  for (int i = 0; i < 8; ++i) ones[i] = (short)0x3F80;  // bf16 1.0

  const int g0 = chunk * (MC / 64);
  const float* bptr = bias + chunk * MC + lc;

  // cooperative stage of 64-key group (g0+it): 20 x 1KB pieces, 5 per wave
  auto stage = [&](int it, int buf) {
    const unsigned short* kg = kc2 + (size_t)(g0 + it) * 6144;
    const unsigned short* vg = vt2 + (size_t)(g0 + it) * 4096;
    unsigned short* lb = lds_kv + buf * 10240;
#pragma unroll
    for (int j5 = 0; j5 < 5; ++j5) {
      int j = w + j5 * 4;
      const unsigned short* src = (j < 12) ? (kg + j * 512) : (vg + (j - 12) * 512);
      __builtin_amdgcn_global_load_lds(
          (const __attribute__((address_space(1))) void*)(src + lane * 8),
          (__attribute__((address_space(3))) void*)(lb + j * 512),
          16, 0, 0);
    }
  };

  floatx4 o[2][4];
#pragma unroll
  for (int a = 0; a < 2; ++a)
#pragma unroll
    for (int nd = 0; nd < 4; ++nd) o[a][nd] = zero;
  floatx4 lacc[2] = {zero, zero};

  unsigned short* slot = &pt[w][0][0];

  stage(0, 0);

#pragma unroll 1
  for (int it = 0; it < NIT; ++it) {
    __syncthreads();                 // stage(it) landed; all prev-iter LDS reads done
    if (it + 1 < NIT) stage(it + 1, (it + 1) & 1);

    const unsigned short* lb = lds_kv + (it & 1) * 10240;
    short8 kf[12];
#pragma unroll
    for (int c = 0; c < 12; ++c)
      kf[c] = *reinterpret_cast<const short8*>(lb + c * 512 + lane * 8);
    short8 vf[8];
#pragma unroll
    for (int c = 0; c < 8; ++c)
      vf[c] = *reinterpret_cast<const short8*>(lb + 6144 + c * 512 + lane * 8);

    // S = Q*K^T, P = exp2(S + bias') -> LDS (C-layout: row=q, col=key)
#pragma unroll
    for (int a = 0; a < 2; ++a) {
#pragma unroll
      for (int nt = 0; nt < 4; ++nt) {
        floatx4 acc = zero;
        acc = mfma16(qf[a][0], kf[nt * 3 + 0], acc);
        acc = mfma16(qf[a][1], kf[nt * 3 + 1], acc);
        acc = mfma16(qf[a][2], kf[nt * 3 + 2], acc);
        float badj = bptr[nt * 16];
#pragma unroll
        for (int r = 0; r < 4; ++r) {
          float p = __builtin_amdgcn_exp2f(acc[r] + badj);
          slot[(lq * 4 + r) * SP + nt * 16 + lc] = f2bf(p);
        }
      }
      // P as A-frags (q-row = lc, 8 consecutive keys) — same-wave DS ordering
      short8 pa0 = *reinterpret_cast<const short8*>(slot + lc * SP + lq * 8);
      short8 pa1 = *reinterpret_cast<const short8*>(slot + lc * SP + 32 + lq * 8);
      lacc[a] = mfma16(pa0, ones, lacc[a]);
      lacc[a] = mfma16(pa1, ones, lacc[a]);
#pragma unroll
      for (int nd = 0; nd < 4; ++nd) {
        o[a][nd] = mfma16(pa0, vf[nd],     o[a][nd]);
        o[a][nd] = mfma16(pa1, vf[4 + nd], o[a][nd]);
      }
    }
    bptr += BN;
  }

  // epilogue: write partial O and l
  const int pb = qt * NC + chunk;
  float* op = opart + (size_t)pb * BQ * D_V;
#pragma unroll
  for (int a = 0; a < 2; ++a) {
    const int rbase = w * 32 + a * 16 + lq * 4;
#pragma unroll
    for (int nd = 0; nd < 4; ++nd)
#pragma unroll
      for (int r = 0; r < 4; ++r)
        op[(rbase + r) * D_V + nd * 16 + lc] = o[a][nd][r];
    if (lc == 0) {
      float* lp = lpart + (size_t)pb * BQ;
#pragma unroll
      for (int r = 0; r < 4; ++r) lp[rbase + r] = lacc[a][r];
    }
  }
}

// ---- final reduction (float4-vectorized) ------------------------------------

template<int NC>
__global__ void reduce_out(const float* __restrict__ opart, const float* __restrict__ lpart,
                           float* __restrict__ out) {
  int t = blockIdx.x * 256 + threadIdx.x;   // 65536 float4s total
  int d4 = t & 15;
  int b = t >> 4;            // q-row 0..4095
  int qt = b >> 7, r = b & 127;
  const floatx4* op4 = reinterpret_cast<const floatx4*>(opart);
  floatx4 os; os[0] = 0.f; os[1] = 0.f; os[2] = 0.f; os[3] = 0.f;
  float ls = 0.f;
#pragma unroll
  for (int c = 0; c < NC; ++c) {
    int row = (qt * NC + c) * BQ + r;
    os += op4[(size_t)row * 16 + d4];
    ls += lpart[row];
  }
  float inv = 1.0f / ls;
  reinterpret_cast<floatx4*>(out)[t] = os * inv;
}

// ---- launcher ---------------------------------------------------------------

template<int NC>
static void launch_all(const float* query, const float* context, const float* keys,
                       const float* values, const float* contexts, const float* ts,
                       const int* used, float* out, char* ws, hipStream_t stream) {
  unsigned short* qc  = (unsigned short*)ws;  ws += (size_t)B_TOT * KD * 2;
  unsigned short* kc2 = (unsigned short*)ws;  ws += (size_t)M_TOT * KD * 2;
  unsigned short* vt2 = (unsigned short*)ws;  ws += (size_t)D_V * M_TOT * 2;
  float* bias  = (float*)ws;                  ws += (size_t)M_TOT * 4;
  float* opart = (float*)ws;                  ws += (size_t)NC * B_TOT * D_V * 4;
  float* lpart = (float*)ws;

  prep_all<<<NB_K + NB_V + NB_Q + NB_B, 256, 0, stream>>>(
      query, context, keys, contexts, values, ts, used, qc, kc2, vt2, bias);

  dim3 grid(NQT, NC);
  flash_kernel<NC><<<grid, 256, 0, stream>>>(qc, kc2, vt2, bias, opart, lpart);

  reduce_out<NC><<<(B_TOT * D_V / 4) / 256, 256, 0, stream>>>(opart, lpart, out);
}

extern "C" void kernel_launch(void* const* d_in, const int* in_sizes, int n_in,
                              void* d_out, int out_size, void* d_ws, size_t ws_size,
                              hipStream_t stream) {
  const float* query    = (const float*)d_in[0];
  const float* context  = (const float*)d_in[1];
  const float* keys     = (const float*)d_in[2];
  const float* values   = (const float*)d_in[3];
  const float* contexts = (const float*)d_in[4];
  const float* ts       = (const float*)d_in[5];
  const int*   used     = (const int*)d_in[6];
  float* out = (float*)d_out;
  char* ws = (char*)d_ws;

  const size_t fixed = (size_t)B_TOT * KD * 2 + (size_t)M_TOT * KD * 2 +
                       (size_t)D_V * M_TOT * 2 + (size_t)M_TOT * 4;
  const size_t need32 = fixed + 32ull * ((size_t)B_TOT * D_V * 4 + (size_t)B_TOT * 4);

  if (ws_size >= need32)
    launch_all<32>(query, context, keys, values, contexts, ts, used, out, ws, stream);
  else
    launch_all<16>(query, context, keys, values, contexts, ts, used, out, ws, stream);
}